// Round 19
// baseline (65.465 us; speedup 1.0000x reference)
//
#include <hip/hip_runtime.h>
#include <math.h>

#define B_  16
#define F_  64
#define C_  64
#define M_  512
#define OC_ 32

typedef float vf4 __attribute__((ext_vector_type(4)));   // clang-native for nt st

// ---------------------------------------------------------------------------
// k1: R15 production version (plain x loads, m-split 4-ways). At its floor.
// ---------------------------------------------------------------------------
__global__ __launch_bounds__(128, 6) void k1_mean(
    const float* __restrict__ x,
    float* __restrict__ s_out, float* __restrict__ rpart)
{
    const int gid = blockIdx.x;        // bc*4 + q
    const int q   = gid & 3;
    const int bc  = gid >> 2;
    const int b   = bc >> 6;
    const int c   = bc & 63;
    const int t   = threadIdx.x;
    const int tf  = t >> 5;
    const int tm  = t & 31;
    const int m4  = (q << 5) + tm;

    const size_t rowbase = ((size_t)b * F_ * C_ + c) * M_;
    float ax = 0.f, ay = 0.f, az = 0.f, aw = 0.f;
    #pragma unroll 8
    for (int j = 0; j < 16; ++j) {
        const int f = (tf << 4) + j;
        const float4 v = ((const float4*)(x + rowbase + (size_t)f * C_ * M_))[m4];
        ax += v.x; ay += v.y; az += v.z; aw += v.w;
    }

    __shared__ float4 red[4][32];
    red[tf][tm] = make_float4(ax, ay, az, aw);
    __syncthreads();

    if (tf == 0) {
        const float4 r1 = red[1][tm], r2 = red[2][tm], r3 = red[3][tm];
        const float inv_f = 1.0f / (float)F_;
        float4 sv;
        sv.x = (ax + r1.x + r2.x + r3.x) * inv_f;
        sv.y = (ay + r1.y + r2.y + r3.y) * inv_f;
        sv.z = (az + r1.z + r2.z + r3.z) * inv_f;
        sv.w = (aw + r1.w + r2.w + r3.w) * inv_f;
        ((float4*)(s_out + (size_t)bc * M_))[m4] = sv;

        float p = sv.x + sv.y + sv.z + sv.w;
        #pragma unroll
        for (int off = 16; off > 0; off >>= 1) p += __shfl_xor(p, off);
        if (t == 0) rpart[gid] = p;
    }
}

// ---------------------------------------------------------------------------
// k2f v2: fused Laplacian + expansion with a 2-DEEP tile pipeline.
// Block = (b, 16-m window), 1024 thr (16 waves), 2 blocks/CU.
// Iteration i: issue load(tile i+2) -> compute(tile i from LDS) ->
// write tile i+1 (in flight for a FULL iteration, ~600-1000 cy) + its deg
// (from regs, 4 shuffles, parity degL) -> B1 -> combine -> B2.
// Loop unrolled x2 with named vA/vB so all register indexing is static.
// Epilogue: 32-channel expansion from LDS, full-64B-line nt stores.
// ---------------------------------------------------------------------------
__global__ __launch_bounds__(1024, 8) void k2_fused(
    const float* __restrict__ A, const float* __restrict__ phys,
    const float* __restrict__ kappa_p, const float* __restrict__ alpha_p,
    const float* __restrict__ s_in, const float* __restrict__ rpart,
    const float* __restrict__ w1, const float* __restrict__ b1,
    const float* __restrict__ w2, const float* __restrict__ b2,
    const float* __restrict__ pw, const float* __restrict__ pb,
    float* __restrict__ out)
{
    __shared__ float Ab[2][4096];      // 32 KB, linear [row j][col c]
    __shared__ float sl[16 * 68];      // sl[mi*68 + j] = s[b, j, m0+mi]
    __shared__ float ph[16 * 68];      // phys, same layout
    __shared__ float snl[64 * 17];     // snl[c*17 + mi]
    __shared__ float redA[16 * 64];    // per-tile As partials
    __shared__ float degL[2][C_];      // parity (deg arrives one tile early)

    const int t   = threadIdx.x;       // 0..1023
    const int blk = blockIdx.x;        // b*32 + window
    const int b   = blk >> 5;
    const int m0  = (blk & 31) << 4;

    // ---- stage s/phys window: thread (c = t>>4, mi = t&15) ----
    {
        const int cc = t >> 4;
        const int mi = t & 15;
        const size_t gg = ((size_t)(b * C_ + cc)) * M_ + m0 + mi;
        sl[mi * 68 + cc] = s_in[gg];
        ph[mi * 68 + cc] = phys[gg];
    }

    // ---- r-MLP (wave 0 keeps r in a register) ----
    float r_c = 0.f;
    if (t < 64) {
        const float4 rp = ((const float4*)rpart)[b * C_ + t];
        const float rin = (rp.x + rp.y + rp.z + rp.w) * (1.0f / (float)M_);
        r_c = b2[0];
        #pragma unroll
        for (int j = 0; j < 16; ++j) {
            float hh = rin * w1[j] + b1[j];
            hh = (hh > 0.f) ? hh : (expf(hh) - 1.f);   // ELU(alpha=1)
            r_c += hh * w2[j];
        }
    }

    const float* Abase = A + (size_t)(b * M_ + m0) * (C_ * C_);
    const int h    = t & 15;           // col-quad within row
    const int rowi = t >> 4;           // staging row 0..63
    const int c    = t & 63;
    const int g    = t >> 6;           // wave id: j-group 4g..4g+3

    // stage tile (regs -> LDS buf) + deg from regs (4 shuffles, 16-group)
    auto stage_and_deg = [&](const float4& vv, int buf) {
        ((float4*)Ab[buf])[t] = vv;
        float p = vv.x + vv.y + vv.z + vv.w;
        p += __shfl_xor(p, 1);
        p += __shfl_xor(p, 2);
        p += __shfl_xor(p, 4);
        p += __shfl_xor(p, 8);
        if (h == 0) degL[buf][rowi] = p;
    };

    // As partial for tile i from LDS buf (conflict-free col reads)
    auto compute = [&](int buf, int i) {
        const float s0 = sl[i * 68 + 4 * g + 0];   // wave-broadcast reads
        const float s1 = sl[i * 68 + 4 * g + 1];
        const float s2 = sl[i * 68 + 4 * g + 2];
        const float s3 = sl[i * 68 + 4 * g + 3];
        const float ap = Ab[buf][(4 * g + 0) * 64 + c] * s0
                       + Ab[buf][(4 * g + 1) * 64 + c] * s1
                       + Ab[buf][(4 * g + 2) * 64 + c] * s2
                       + Ab[buf][(4 * g + 3) * 64 + c] * s3;
        redA[g * 64 + c] = ap;
    };

    const float kcoef = log1pf(expf(kappa_p[0]));      // softplus(kappa)
    const float al    = alpha_p[0];

    auto combine = [&](int buf, int i) {
        if (t < 64) {
            float As = 0.f;
            #pragma unroll
            for (int q2 = 0; q2 < 16; ++q2) As += redA[q2 * 64 + t];
            const float dg   = degL[buf][t];
            const float sval = sl[i * 68 + t];
            const float pv   = ph[i * 68 + t];
            snl[t * 17 + i] = sval - kcoef * (dg * sval - As) + (r_c + al * pv);
        }
    };

    // ---- prologue: tile0 staged, tile1 in flight ----
    float4 vA = ((const float4*)Abase)[t];             // tile 0
    stage_and_deg(vA, 0);
    float4 vB = ((const float4*)(Abase + 4096))[t];    // tile 1 (issued)
    __syncthreads();                                   // Ab[0], sl, ph, degL[0]

    #pragma unroll 1
    for (int ii = 0; ii < 8; ++ii) {
        const int i0 = 2 * ii;
        // ---- even phase: cur buf 0 ----
        if (i0 + 2 < 16)
            vA = ((const float4*)(Abase + (size_t)(i0 + 2) * 4096))[t];
        compute(0, i0);
        stage_and_deg(vB, 1);          // tile i0+1 (in flight ~1 full iter)
        __syncthreads();               // B1
        combine(0, i0);
        __syncthreads();               // B2

        // ---- odd phase: cur buf 1 ----
        const int i1 = i0 + 1;
        if (i1 + 2 < 16)
            vB = ((const float4*)(Abase + (size_t)(i1 + 2) * 4096))[t];
        compute(1, i1);
        if (i1 + 1 < 16)
            stage_and_deg(vA, 0);      // tile i1+1
        __syncthreads();               // B1
        combine(1, i1);
        __syncthreads();               // B2
    }

    // ---- epilogue: out[b,o,c,m0..m0+15], full-64B-line nt stores ----
    #pragma unroll
    for (int i = 0; i < 8; ++i) {
        const int idx = (i << 10) + t;     // o*256 + c*4 + mq
        const int mq  = idx & 3;
        const int cc  = (idx >> 2) & 63;
        const int o   = idx >> 8;
        const float w  = pw[o];
        const float bb = pb[o];
        vf4 ov;
        ov.x = snl[cc * 17 + mq * 4 + 0] * w + bb;
        ov.y = snl[cc * 17 + mq * 4 + 1] * w + bb;
        ov.z = snl[cc * 17 + mq * 4 + 2] * w + bb;
        ov.w = snl[cc * 17 + mq * 4 + 3] * w + bb;
        __builtin_nontemporal_store(ov,
            (vf4*)(out + (((size_t)(b * OC_ + o)) * C_ + cc) * M_ + m0 + mq * 4));
    }
}

extern "C" void kernel_launch(void* const* d_in, const int* in_sizes, int n_in,
                              void* d_out, int out_size, void* d_ws, size_t ws_size,
                              hipStream_t stream)
{
    const float* x     = (const float*)d_in[0];
    const float* A     = (const float*)d_in[1];
    const float* phys  = (const float*)d_in[2];
    const float* kappa = (const float*)d_in[3];
    const float* alpha = (const float*)d_in[4];
    const float* w1    = (const float*)d_in[5];
    const float* b1    = (const float*)d_in[6];
    const float* w2    = (const float*)d_in[7];
    const float* b2    = (const float*)d_in[8];
    const float* pw    = (const float*)d_in[9];
    const float* pb    = (const float*)d_in[10];
    float* out = (float*)d_out;

    float* ws    = (float*)d_ws;
    float* s     = ws;                            // B*C*M
    float* rpart = ws + (size_t)B_ * C_ * M_;     // B*C*4 (16B-aligned)

    k1_mean<<<B_ * C_ * 4, 128, 0, stream>>>(x, s, rpart);
    k2_fused<<<B_ * (M_ / 16), 1024, 0, stream>>>(A, phys, kappa, alpha, s, rpart,
                                                  w1, b1, w2, b2, pw, pb, out);
}